// Round 1
// baseline (2318.768 us; speedup 1.0000x reference)
//
#include <hip/hip_runtime.h>
#include <hip/hip_bf16.h>

typedef int v4i __attribute__((ext_vector_type(4)));

#define DEV __device__ __forceinline__

// ---------------- block reductions (blockDim == 256) ----------------
DEV float block_sum256(float v, float* red){
#pragma unroll
  for (int o=32;o>0;o>>=1) v += __shfl_down(v,o);
  int w = threadIdx.x>>6;
  if ((threadIdx.x&63)==0) red[w]=v;
  __syncthreads();
  v = red[0]+red[1]+red[2]+red[3];
  __syncthreads();
  return v;
}
DEV float block_max256(float v, float* red){
#pragma unroll
  for (int o=32;o>0;o>>=1) v = fmaxf(v,__shfl_down(v,o));
  int w = threadIdx.x>>6;
  if ((threadIdx.x&63)==0) red[w]=v;
  __syncthreads();
  v = fmaxf(fmaxf(red[0],red[1]),fmaxf(red[2],red[3]));
  __syncthreads();
  return v;
}

// ---------------- weight scale reduction ----------------
__global__ __launch_bounds__(256) void reduce_abs_kernel(const float* __restrict__ w, long n4,
                                                         float* __restrict__ partials){
  __shared__ float red[4];
  const float4* w4 = (const float4*)w;
  float s = 0.f;
  for (long i = (long)blockIdx.x*256 + threadIdx.x; i < n4; i += (long)gridDim.x*256){
    float4 v = w4[i];
    s += fabsf(v.x)+fabsf(v.y)+fabsf(v.z)+fabsf(v.w);
  }
  s = block_sum256(s, red);
  if (threadIdx.x==0) partials[blockIdx.x]=s;
}

__global__ __launch_bounds__(256) void finalize_scales_kernel(const float* __restrict__ partials,
                                                              float* __restrict__ hdr){
  __shared__ float red[4];
  float s1=0.f, s2=0.f;
  for (int i=threadIdx.x;i<1024;i+=256){ s1+=partials[i]; s2+=partials[i+1024]; }
  s1 = block_sum256(s1, red);
  s2 = block_sum256(s2, red);
  if (threadIdx.x==0){
    float m1 = s1 / 23068672.0f;            // mean |w_gate|
    float sc1 = 1.0f / fmaxf(m1, 1e-5f);
    hdr[0]=sc1; hdr[1]=1.0f/sc1;
    float m2 = s2 / 11534336.0f;            // mean |w_down|
    float sc2 = 1.0f / fmaxf(m2, 1e-5f);
    hdr[2]=sc2; hdr[3]=1.0f/sc2;
  }
}

// ---------------- ternary weight quant ----------------
__global__ __launch_bounds__(256) void quant_w_kernel(const float* __restrict__ w,
                                                      signed char* __restrict__ wq, long n4,
                                                      const float* __restrict__ hdr, int hi){
  float scale = hdr[hi];
  const float4* w4 = (const float4*)w;
  unsigned* o4 = (unsigned*)wq;
  for (long i = (long)blockIdx.x*256 + threadIdx.x; i < n4; i += (long)gridDim.x*256){
    float4 v = w4[i];
    int q0 = (int)fminf(fmaxf(rintf(v.x*scale),-1.f),1.f);
    int q1 = (int)fminf(fmaxf(rintf(v.y*scale),-1.f),1.f);
    int q2 = (int)fminf(fmaxf(rintf(v.z*scale),-1.f),1.f);
    int q3 = (int)fminf(fmaxf(rintf(v.w*scale),-1.f),1.f);
    unsigned pk = (q0&0xff) | ((q1&0xff)<<8) | ((q2&0xff)<<16) | ((q3&0xff)<<24);
    o4[i] = pk;
  }
}

// ---------------- RMSNorm + act quant (fp32 input, D=2048) ----------------
__global__ __launch_bounds__(256) void rms_quant_x_kernel(const float* __restrict__ x,
                                                          const float* __restrict__ g,
                                                          signed char* __restrict__ xq,
                                                          float* __restrict__ isx){
  __shared__ float red[4];
  const int row = blockIdx.x, t = threadIdx.x;
  const float* xr = x + (size_t)row*2048 + t*8;
  float4 a = *(const float4*)xr;
  float4 b = *(const float4*)(xr+4);
  float xv[8] = {a.x,a.y,a.z,a.w,b.x,b.y,b.z,b.w};
  float ss = 0.f;
#pragma unroll
  for (int i=0;i<8;i++) ss += xv[i]*xv[i];
  ss = block_sum256(ss, red);
  float rs = rsqrtf(ss*(1.0f/2048.0f) + 1e-6f);
  const float* gr = g + t*8;
  float4 ga = *(const float4*)gr;
  float4 gb = *(const float4*)(gr+4);
  float gv[8] = {ga.x,ga.y,ga.z,ga.w,gb.x,gb.y,gb.z,gb.w};
  float xn[8]; float m = 0.f;
#pragma unroll
  for (int i=0;i<8;i++){ xn[i] = xv[i]*rs*gv[i]; m = fmaxf(m, fabsf(xn[i])); }
  m = block_max256(m, red);
  float scale = 127.0f / fmaxf(m, 1e-5f);
  unsigned long long pk = 0;
#pragma unroll
  for (int i=0;i<8;i++){
    int q = (int)fminf(fmaxf(rintf(xn[i]*scale), -128.0f), 127.0f);
    pk |= (unsigned long long)(unsigned char)(signed char)q << (8*i);
  }
  *(unsigned long long*)(xq + (size_t)row*2048 + t*8) = pk;
  if (t==0) isx[row] = 1.0f/scale;
}

// ---------------- RMSNorm + act quant (bf16 swiglu input, I=5632) ----------------
__global__ __launch_bounds__(256) void rms_quant_sg_kernel(const __hip_bfloat16* __restrict__ sg,
                                                           const float* __restrict__ g,
                                                           signed char* __restrict__ xq,
                                                           float* __restrict__ isx){
  __shared__ float red[4];
  const int row = blockIdx.x, t = threadIdx.x;
  const unsigned* sr = (const unsigned*)(sg + (size_t)row*5632);
  float s[22];
  float ss = 0.f;
#pragma unroll
  for (int i=0;i<11;i++){
    unsigned u = sr[t + i*256];
    float f0 = __uint_as_float(u<<16);
    float f1 = __uint_as_float(u & 0xffff0000u);
    s[2*i]=f0; s[2*i+1]=f1;
    ss += f0*f0 + f1*f1;
  }
  ss = block_sum256(ss, red);
  float rs = rsqrtf(ss*(1.0f/5632.0f) + 1e-6f);
  const float2* g2 = (const float2*)g;
  float xn[22]; float m = 0.f;
#pragma unroll
  for (int i=0;i<11;i++){
    float2 gv = g2[t + i*256];
    xn[2*i]   = s[2*i]  *rs*gv.x;
    xn[2*i+1] = s[2*i+1]*rs*gv.y;
    m = fmaxf(m, fmaxf(fabsf(xn[2*i]), fabsf(xn[2*i+1])));
  }
  m = block_max256(m, red);
  float scale = 127.0f / fmaxf(m, 1e-5f);
  short* o2 = (short*)(xq + (size_t)row*5632);
#pragma unroll
  for (int i=0;i<11;i++){
    int q0 = (int)fminf(fmaxf(rintf(xn[2*i]  *scale), -128.0f), 127.0f);
    int q1 = (int)fminf(fmaxf(rintf(xn[2*i+1]*scale), -128.0f), 127.0f);
    o2[t + i*256] = (short)((q0 & 0xff) | ((q1 & 0xff) << 8));
  }
  if (t==0) isx[row] = 1.0f/scale;
}

// ---------------- GEMM1: int8 MFMA + fused swiglu epilogue ----------------
// A: xq1 [16384][2048], B: wq_gate [11264][2048]
// block computes gate cols [bc0,bc0+128) (waves 0-3) and v cols [5632+bc0,...) (waves 4-7)
// out: swiglu bf16 [16384][5632]
__global__ __launch_bounds__(512) void gemm1_swiglu_kernel(const signed char* __restrict__ A,
                                                           const signed char* __restrict__ B,
                                                           const float* __restrict__ inv_sx,
                                                           const float* __restrict__ hdr,
                                                           __hip_bfloat16* __restrict__ out){
  constexpr int K = 2048;
  constexpr int NI = 5632;
  __shared__ __align__(16) unsigned char smem[65536];
  signed char* As = (signed char*)smem;           // [128][128] 16KB
  signed char* Bs = (signed char*)smem + 16384;   // [2][128][128] 32KB
  float* vex = (float*)smem;                      // [128][128] f32, reused after K-loop

  const int t = threadIdx.x;
  const int bm0 = blockIdx.y * 128;
  const int bc0 = blockIdx.x * 128;
  const int w = t >> 6, l = t & 63;
  const int ts = w >> 2;          // 0 = gate waves, 1 = v waves
  const int wv = w & 3;
  const int wr = (wv >> 1) * 64, wc = (wv & 1) * 64;
  const int lr = l & 15, lg = l >> 4;

  const float inv_sw = hdr[1];
  v4i acc[4][4] = {};

  for (int kt = 0; kt < K/128; ++kt){
    int4 ra[2], rb[4];
#pragma unroll
    for (int i=0;i<2;i++){
      int c = t + i*512; int r = c>>3, k16 = c&7;
      ra[i] = *(const int4*)(A + (size_t)(bm0 + r)*K + kt*128 + k16*16);
    }
#pragma unroll
    for (int i=0;i<4;i++){
      int c = t + i*512; int tile = c>>10, r = (c>>3)&127, k16 = c&7;
      int grow = (tile ? NI : 0) + bc0 + r;
      rb[i] = *(const int4*)(B + (size_t)grow*K + kt*128 + k16*16);
    }
    __syncthreads();
#pragma unroll
    for (int i=0;i<2;i++) *(int4*)(As + (t + i*512)*16) = ra[i];
#pragma unroll
    for (int i=0;i<4;i++) *(int4*)(Bs + (t + i*512)*16) = rb[i];
    __syncthreads();
#pragma unroll
    for (int kk=0;kk<2;++kk){
      v4i af[4], bf[4];
#pragma unroll
      for (int i=0;i<4;i++) af[i] = *(const v4i*)(As + (wr + i*16 + lr)*128 + kk*64 + lg*16);
#pragma unroll
      for (int j=0;j<4;j++) bf[j] = *(const v4i*)(Bs + ts*16384 + (wc + j*16 + lr)*128 + kk*64 + lg*16);
#pragma unroll
      for (int i=0;i<4;i++)
#pragma unroll
        for (int j=0;j<4;j++)
          acc[i][j] = __builtin_amdgcn_mfma_i32_16x16x64_i8(af[i], bf[j], acc[i][j], 0, 0, 0);
    }
  }
  __syncthreads();          // all tile reads done; smem reusable as vex
  if (ts == 1){             // v waves: write dequantized v
#pragma unroll
    for (int i=0;i<4;i++){
#pragma unroll
      for (int r=0;r<4;r++){
        int lrow = wr + i*16 + lg*4 + r;
        float f = inv_sx[bm0 + lrow] * inv_sw;
#pragma unroll
        for (int j=0;j<4;j++)
          vex[lrow*128 + wc + j*16 + lr] = (float)acc[i][j][r] * f;
      }
    }
  }
  __syncthreads();
  if (ts == 0){             // gate waves: swish(gate)*v -> bf16
#pragma unroll
    for (int i=0;i<4;i++){
#pragma unroll
      for (int r=0;r<4;r++){
        int lrow = wr + i*16 + lg*4 + r;
        float f = inv_sx[bm0 + lrow] * inv_sw;
        size_t orow = (size_t)(bm0 + lrow) * NI + bc0;
#pragma unroll
        for (int j=0;j<4;j++){
          float gv = (float)acc[i][j][r] * f;
          float vv = vex[lrow*128 + wc + j*16 + lr];
          float sw = gv / (1.0f + expf(-gv)) * vv;
          out[orow + wc + j*16 + lr] = __float2bfloat16(sw);
        }
      }
    }
  }
}

// ---------------- GEMM2: int8 MFMA, fp32 out ----------------
// A: xq2 [16384][5632], B: wq_down [2048][5632], out fp32 [16384][2048]
__global__ __launch_bounds__(256) void gemm2_kernel(const signed char* __restrict__ A,
                                                    const signed char* __restrict__ B,
                                                    const float* __restrict__ inv_sx,
                                                    const float* __restrict__ hdr,
                                                    float* __restrict__ out){
  constexpr int K = 5632;
  constexpr int N = 2048;
  __shared__ __align__(16) signed char As[16384];
  __shared__ __align__(16) signed char Bs[16384];
  const int t = threadIdx.x;
  const int bm0 = blockIdx.y * 128;
  const int bn0 = blockIdx.x * 128;
  const int w = t >> 6, l = t & 63;
  const int wr = (w >> 1) * 64, wc = (w & 1) * 64;
  const int lr = l & 15, lg = l >> 4;

  const float inv_sw = hdr[3];
  v4i acc[4][4] = {};

  for (int kt = 0; kt < K/128; ++kt){
    int4 ra[4], rb[4];
#pragma unroll
    for (int i=0;i<4;i++){
      int c = t + i*256; int r = c>>3, k16 = c&7;
      ra[i] = *(const int4*)(A + (size_t)(bm0 + r)*K + kt*128 + k16*16);
      rb[i] = *(const int4*)(B + (size_t)(bn0 + r)*K + kt*128 + k16*16);
    }
    __syncthreads();
#pragma unroll
    for (int i=0;i<4;i++){
      *(int4*)(As + (t + i*256)*16) = ra[i];
      *(int4*)(Bs + (t + i*256)*16) = rb[i];
    }
    __syncthreads();
#pragma unroll
    for (int kk=0;kk<2;++kk){
      v4i af[4], bf[4];
#pragma unroll
      for (int i=0;i<4;i++) af[i] = *(const v4i*)(As + (wr + i*16 + lr)*128 + kk*64 + lg*16);
#pragma unroll
      for (int j=0;j<4;j++) bf[j] = *(const v4i*)(Bs + (wc + j*16 + lr)*128 + kk*64 + lg*16);
#pragma unroll
      for (int i=0;i<4;i++)
#pragma unroll
        for (int j=0;j<4;j++)
          acc[i][j] = __builtin_amdgcn_mfma_i32_16x16x64_i8(af[i], bf[j], acc[i][j], 0, 0, 0);
    }
  }
#pragma unroll
  for (int i=0;i<4;i++){
#pragma unroll
    for (int r=0;r<4;r++){
      int lrow = wr + i*16 + lg*4 + r;
      float f = inv_sx[bm0 + lrow] * inv_sw;
      size_t o = (size_t)(bm0 + lrow) * N + bn0;
#pragma unroll
      for (int j=0;j<4;j++)
        out[o + wc + j*16 + lr] = (float)acc[i][j][r] * f;
    }
  }
}

// ---------------- launch ----------------
extern "C" void kernel_launch(void* const* d_in, const int* in_sizes, int n_in,
                              void* d_out, int out_size, void* d_ws, size_t ws_size,
                              hipStream_t stream) {
  const float* x      = (const float*)d_in[0];   // [4,4096,2048]
  const float* w_gate = (const float*)d_in[1];   // [11264,2048]
  const float* g_gate = (const float*)d_in[2];   // [2048]
  const float* w_down = (const float*)d_in[3];   // [2048,5632]
  const float* g_down = (const float*)d_in[4];   // [5632]
  float* out = (float*)d_out;                    // [4,4096,2048]

  char* p = (char*)d_ws;
  float* hdr      = (float*)p;          // [0]=sc_wg [1]=1/sc_wg [2]=sc_wd [3]=1/sc_wd
  float* partials = (float*)(p + 64);   // 2048 floats
  size_t off = 8448;
  signed char* wqg = (signed char*)(p + off); off += 23068672;   // [11264][2048]
  signed char* wqd = (signed char*)(p + off); off += 11534336;   // [2048][5632]
  signed char* xq1 = (signed char*)(p + off); off += 33554432;   // [16384][2048]
  signed char* xq2 = (signed char*)(p + off); off += 92274688;   // [16384][5632]
  float* isx1 = (float*)(p + off); off += 65536;
  float* isx2 = (float*)(p + off); off += 65536;
  __hip_bfloat16* sg = (__hip_bfloat16*)(p + off); off += 184549376; // [16384][5632]

  reduce_abs_kernel<<<1024,256,0,stream>>>(w_gate, 23068672/4, partials);
  reduce_abs_kernel<<<1024,256,0,stream>>>(w_down, 11534336/4, partials+1024);
  finalize_scales_kernel<<<1,256,0,stream>>>(partials, hdr);
  quant_w_kernel<<<2048,256,0,stream>>>(w_gate, wqg, 23068672/4, hdr, 0);
  quant_w_kernel<<<1024,256,0,stream>>>(w_down, wqd, 11534336/4, hdr, 2);
  rms_quant_x_kernel<<<16384,256,0,stream>>>(x, g_gate, xq1, isx1);
  gemm1_swiglu_kernel<<<dim3(44,128),512,0,stream>>>(xq1, wqg, isx1, hdr, sg);
  rms_quant_sg_kernel<<<16384,256,0,stream>>>(sg, g_down, xq2, isx2);
  gemm2_kernel<<<dim3(16,128),256,0,stream>>>(xq2, wqd, isx2, hdr, out);
}

// Round 2
// 1047.723 us; speedup vs baseline: 2.2131x; 2.2131x over previous
//
#include <hip/hip_runtime.h>
#include <hip/hip_bf16.h>

typedef int v4i __attribute__((ext_vector_type(4)));

#define DEV __device__ __forceinline__

DEV void gload16(const void* g, void* l){
  __builtin_amdgcn_global_load_lds((const __attribute__((address_space(1))) unsigned int*)g,
                                   (__attribute__((address_space(3))) unsigned int*)l, 16, 0, 0);
}

// ---------------- block reductions (blockDim == 256) ----------------
DEV float block_sum256(float v, float* red){
#pragma unroll
  for (int o=32;o>0;o>>=1) v += __shfl_down(v,o);
  int w = threadIdx.x>>6;
  if ((threadIdx.x&63)==0) red[w]=v;
  __syncthreads();
  v = red[0]+red[1]+red[2]+red[3];
  __syncthreads();
  return v;
}
DEV float block_max256(float v, float* red){
#pragma unroll
  for (int o=32;o>0;o>>=1) v = fmaxf(v,__shfl_down(v,o));
  int w = threadIdx.x>>6;
  if ((threadIdx.x&63)==0) red[w]=v;
  __syncthreads();
  v = fmaxf(fmaxf(red[0],red[1]),fmaxf(red[2],red[3]));
  __syncthreads();
  return v;
}

// ---------------- weight scale reduction ----------------
__global__ __launch_bounds__(256) void reduce_abs_kernel(const float* __restrict__ w, long n4,
                                                         float* __restrict__ partials){
  __shared__ float red[4];
  const float4* w4 = (const float4*)w;
  float s = 0.f;
  for (long i = (long)blockIdx.x*256 + threadIdx.x; i < n4; i += (long)gridDim.x*256){
    float4 v = w4[i];
    s += fabsf(v.x)+fabsf(v.y)+fabsf(v.z)+fabsf(v.w);
  }
  s = block_sum256(s, red);
  if (threadIdx.x==0) partials[blockIdx.x]=s;
}

__global__ __launch_bounds__(256) void finalize_scales_kernel(const float* __restrict__ partials,
                                                              float* __restrict__ hdr){
  __shared__ float red[4];
  float s1=0.f, s2=0.f;
  for (int i=threadIdx.x;i<1024;i+=256){ s1+=partials[i]; s2+=partials[i+1024]; }
  s1 = block_sum256(s1, red);
  s2 = block_sum256(s2, red);
  if (threadIdx.x==0){
    float m1 = s1 / 23068672.0f;            // mean |w_gate|
    float sc1 = 1.0f / fmaxf(m1, 1e-5f);
    hdr[0]=sc1; hdr[1]=1.0f/sc1;
    float m2 = s2 / 11534336.0f;            // mean |w_down|
    float sc2 = 1.0f / fmaxf(m2, 1e-5f);
    hdr[2]=sc2; hdr[3]=1.0f/sc2;
  }
}

// ---------------- ternary weight quant ----------------
__global__ __launch_bounds__(256) void quant_w_kernel(const float* __restrict__ w,
                                                      signed char* __restrict__ wq, long n4,
                                                      const float* __restrict__ hdr, int hi){
  float scale = hdr[hi];
  const float4* w4 = (const float4*)w;
  unsigned* o4 = (unsigned*)wq;
  for (long i = (long)blockIdx.x*256 + threadIdx.x; i < n4; i += (long)gridDim.x*256){
    float4 v = w4[i];
    int q0 = (int)fminf(fmaxf(rintf(v.x*scale),-1.f),1.f);
    int q1 = (int)fminf(fmaxf(rintf(v.y*scale),-1.f),1.f);
    int q2 = (int)fminf(fmaxf(rintf(v.z*scale),-1.f),1.f);
    int q3 = (int)fminf(fmaxf(rintf(v.w*scale),-1.f),1.f);
    unsigned pk = (q0&0xff) | ((q1&0xff)<<8) | ((q2&0xff)<<16) | ((q3&0xff)<<24);
    o4[i] = pk;
  }
}

// ---------------- RMSNorm + act quant (fp32 input, D=2048) ----------------
__global__ __launch_bounds__(256) void rms_quant_x_kernel(const float* __restrict__ x,
                                                          const float* __restrict__ g,
                                                          signed char* __restrict__ xq,
                                                          float* __restrict__ isx){
  __shared__ float red[4];
  const int row = blockIdx.x, t = threadIdx.x;
  const float* xr = x + (size_t)row*2048 + t*8;
  float4 a = *(const float4*)xr;
  float4 b = *(const float4*)(xr+4);
  float xv[8] = {a.x,a.y,a.z,a.w,b.x,b.y,b.z,b.w};
  float ss = 0.f;
#pragma unroll
  for (int i=0;i<8;i++) ss += xv[i]*xv[i];
  ss = block_sum256(ss, red);
  float rs = rsqrtf(ss*(1.0f/2048.0f) + 1e-6f);
  const float* gr = g + t*8;
  float4 ga = *(const float4*)gr;
  float4 gb = *(const float4*)(gr+4);
  float gv[8] = {ga.x,ga.y,ga.z,ga.w,gb.x,gb.y,gb.z,gb.w};
  float xn[8]; float m = 0.f;
#pragma unroll
  for (int i=0;i<8;i++){ xn[i] = xv[i]*rs*gv[i]; m = fmaxf(m, fabsf(xn[i])); }
  m = block_max256(m, red);
  float scale = 127.0f / fmaxf(m, 1e-5f);
  unsigned long long pk = 0;
#pragma unroll
  for (int i=0;i<8;i++){
    int q = (int)fminf(fmaxf(rintf(xn[i]*scale), -128.0f), 127.0f);
    pk |= (unsigned long long)(unsigned char)(signed char)q << (8*i);
  }
  *(unsigned long long*)(xq + (size_t)row*2048 + t*8) = pk;
  if (t==0) isx[row] = 1.0f/scale;
}

// ---------------- RMSNorm + act quant (bf16 swiglu input, I=5632) ----------------
__global__ __launch_bounds__(256) void rms_quant_sg_kernel(const __hip_bfloat16* __restrict__ sg,
                                                           const float* __restrict__ g,
                                                           signed char* __restrict__ xq,
                                                           float* __restrict__ isx){
  __shared__ float red[4];
  const int row = blockIdx.x, t = threadIdx.x;
  const unsigned* sr = (const unsigned*)(sg + (size_t)row*5632);
  float s[22];
  float ss = 0.f;
#pragma unroll
  for (int i=0;i<11;i++){
    unsigned u = sr[t + i*256];
    float f0 = __uint_as_float(u<<16);
    float f1 = __uint_as_float(u & 0xffff0000u);
    s[2*i]=f0; s[2*i+1]=f1;
    ss += f0*f0 + f1*f1;
  }
  ss = block_sum256(ss, red);
  float rs = rsqrtf(ss*(1.0f/5632.0f) + 1e-6f);
  const float2* g2 = (const float2*)g;
  float xn[22]; float m = 0.f;
#pragma unroll
  for (int i=0;i<11;i++){
    float2 gv = g2[t + i*256];
    xn[2*i]   = s[2*i]  *rs*gv.x;
    xn[2*i+1] = s[2*i+1]*rs*gv.y;
    m = fmaxf(m, fmaxf(fabsf(xn[2*i]), fabsf(xn[2*i+1])));
  }
  m = block_max256(m, red);
  float scale = 127.0f / fmaxf(m, 1e-5f);
  short* o2 = (short*)(xq + (size_t)row*5632);
#pragma unroll
  for (int i=0;i<11;i++){
    int q0 = (int)fminf(fmaxf(rintf(xn[2*i]  *scale), -128.0f), 127.0f);
    int q1 = (int)fminf(fmaxf(rintf(xn[2*i+1]*scale), -128.0f), 127.0f);
    o2[t + i*256] = (short)((q0 & 0xff) | ((q1 & 0xff) << 8));
  }
  if (t==0) isx[row] = 1.0f/scale;
}

// ---------------- GEMM1: int8 MFMA + fused swiglu epilogue ----------------
// A: xq1 [16384][2048], B: wq_gate [11264][2048]
// waves 0-3 compute gate cols [bc0,bc0+128), waves 4-7 v cols [5632+bc0,...)
// LDS tiles XOR-swizzled (k16 ^= row&7); staged via global_load_lds with
// inverse-swizzled global source (linear LDS dest, rule #21).
__global__ __launch_bounds__(512) void gemm1_swiglu_kernel(const signed char* __restrict__ A,
                                                           const signed char* __restrict__ B,
                                                           const float* __restrict__ inv_sx,
                                                           const float* __restrict__ hdr,
                                                           __hip_bfloat16* __restrict__ out){
  constexpr int K = 2048;
  constexpr int NI = 5632;
  __shared__ __align__(16) unsigned char smem[65536];
  signed char* As = (signed char*)smem;           // [128][128] 16KB
  signed char* Bs = (signed char*)smem + 16384;   // [2][128][128] 32KB
  float* vex = (float*)smem;                      // [128][128] f32, reused after K-loop

  const int t = threadIdx.x;
  const int lid = blockIdx.x + blockIdx.y * gridDim.x;  // 0..5631
  const int nid = (lid & 7) * 704 + (lid >> 3);         // bijective XCD swizzle (5632%8==0)
  const int bm0 = (nid / 44) * 128;
  const int bc0 = (nid % 44) * 128;
  const int w = t >> 6, l = t & 63;
  const int ts = w >> 2;          // 0 = gate waves, 1 = v waves
  const int wv = w & 3;
  const int wr = (wv >> 1) * 64, wc = (wv & 1) * 64;
  const int lr = l & 15, lg = l >> 4;

  const float inv_sw = hdr[1];

  // staging addresses (source carries the inverse swizzle)
  const signed char* aSrc[2]; signed char* aDst[2];
#pragma unroll
  for (int i=0;i<2;i++){
    int c = t + i*512; int r = c>>3, k = c&7;
    aSrc[i] = A + (size_t)(bm0 + r)*K + (k ^ (r&7))*16;
    aDst[i] = As + c*16;
  }
  const signed char* bSrc[4]; signed char* bDst[4];
#pragma unroll
  for (int i=0;i<4;i++){
    int c = t + i*512; int tile = c>>10, r = (c>>3)&127, k = c&7;
    int grow = (tile ? NI : 0) + bc0 + r;
    bSrc[i] = B + (size_t)grow*K + (k ^ (r&7))*16;
    bDst[i] = Bs + c*16;
  }

  v4i acc[4][4] = {};

  for (int kt = 0; kt < K/128; ++kt){
#pragma unroll
    for (int i=0;i<2;i++) gload16(aSrc[i] + kt*128, aDst[i]);
#pragma unroll
    for (int i=0;i<4;i++) gload16(bSrc[i] + kt*128, bDst[i]);
    __syncthreads();     // compiler emits vmcnt(0) drain before barrier
#pragma unroll
    for (int kk=0;kk<2;++kk){
      v4i af[4], bf[4];
#pragma unroll
      for (int i=0;i<4;i++){
        int row = wr + i*16 + lr;
        af[i] = *(const v4i*)(As + row*128 + (((kk*4+lg) ^ (row&7))*16));
      }
#pragma unroll
      for (int j=0;j<4;j++){
        int row = wc + j*16 + lr;
        bf[j] = *(const v4i*)(Bs + ts*16384 + row*128 + (((kk*4+lg) ^ (row&7))*16));
      }
#pragma unroll
      for (int i=0;i<4;i++)
#pragma unroll
        for (int j=0;j<4;j++)
          acc[i][j] = __builtin_amdgcn_mfma_i32_16x16x64_i8(af[i], bf[j], acc[i][j], 0, 0, 0);
    }
    __syncthreads();
  }

  // --- epilogue: v exchange (f32) -> swish -> bf16 tile -> coalesced store ---
  if (ts == 1){
#pragma unroll
    for (int i=0;i<4;i++){
#pragma unroll
      for (int r=0;r<4;r++){
        int lrow = wr + i*16 + lg*4 + r;
        float f = inv_sx[bm0 + lrow] * inv_sw;
#pragma unroll
        for (int j=0;j<4;j++)
          vex[lrow*128 + wc + j*16 + lr] = (float)acc[i][j][r] * f;
      }
    }
  }
  __syncthreads();
  if (ts == 0){             // compute swiglu into acc (reuse regs as f32 bits)
#pragma unroll
    for (int i=0;i<4;i++){
#pragma unroll
      for (int r=0;r<4;r++){
        int lrow = wr + i*16 + lg*4 + r;
        float f = inv_sx[bm0 + lrow] * inv_sw;
#pragma unroll
        for (int j=0;j<4;j++){
          float gv = (float)acc[i][j][r] * f;
          float vv = vex[lrow*128 + wc + j*16 + lr];
          float sw = gv / (1.0f + expf(-gv)) * vv;
          acc[i][j][r] = __float_as_int(sw);
        }
      }
    }
  }
  __syncthreads();          // all vex reads done; smem reusable as bf16 tile
  __hip_bfloat16* obuf = (__hip_bfloat16*)smem;   // [128][128] bf16, 32KB
  if (ts == 0){
#pragma unroll
    for (int i=0;i<4;i++){
#pragma unroll
      for (int r=0;r<4;r++){
        int lrow = wr + i*16 + lg*4 + r;
#pragma unroll
        for (int j=0;j<4;j++)
          obuf[lrow*128 + wc + j*16 + lr] = __float2bfloat16(__int_as_float(acc[i][j][r]));
      }
    }
  }
  __syncthreads();
  // coalesced store: 16B/lane, 256B per row segment
#pragma unroll
  for (int it=0; it<4; ++it){
    int idx = t + it*512;
    int row = idx >> 4, c16 = idx & 15;
    *(int4*)((char*)(out + (size_t)(bm0+row)*NI + bc0) + c16*16) =
        *(const int4*)((const char*)obuf + row*256 + c16*16);
  }
}

// ---------------- GEMM2: int8 MFMA, fp32 out ----------------
// A: xq2 [16384][5632], B: wq_down [2048][5632], out fp32 [16384][2048]
__global__ __launch_bounds__(256) void gemm2_kernel(const signed char* __restrict__ A,
                                                    const signed char* __restrict__ B,
                                                    const float* __restrict__ inv_sx,
                                                    const float* __restrict__ hdr,
                                                    float* __restrict__ out){
  constexpr int K = 5632;
  constexpr int N = 2048;
  __shared__ __align__(16) signed char As[16384];
  __shared__ __align__(16) signed char Bs[16384];
  const int t = threadIdx.x;
  const int lid = blockIdx.x + blockIdx.y * gridDim.x;  // 0..2047
  const int nid = (lid & 7) * 256 + (lid >> 3);         // bijective XCD swizzle (2048%8==0)
  const int bm0 = (nid >> 4) * 128;
  const int bn0 = (nid & 15) * 128;
  const int w = t >> 6, l = t & 63;
  const int wr = (w >> 1) * 64, wc = (w & 1) * 64;
  const int lr = l & 15, lg = l >> 4;

  const float inv_sw = hdr[3];

  const signed char *aSrc[4], *bSrc[4]; signed char *aDst[4], *bDst[4];
#pragma unroll
  for (int i=0;i<4;i++){
    int c = t + i*256; int r = c>>3, k = c&7;
    aSrc[i] = A + (size_t)(bm0 + r)*K + (k ^ (r&7))*16;
    bSrc[i] = B + (size_t)(bn0 + r)*K + (k ^ (r&7))*16;
    aDst[i] = As + c*16;
    bDst[i] = Bs + c*16;
  }

  v4i acc[4][4] = {};

  for (int kt = 0; kt < K/128; ++kt){
#pragma unroll
    for (int i=0;i<4;i++){
      gload16(aSrc[i] + kt*128, aDst[i]);
      gload16(bSrc[i] + kt*128, bDst[i]);
    }
    __syncthreads();
#pragma unroll
    for (int kk=0;kk<2;++kk){
      v4i af[4], bf[4];
#pragma unroll
      for (int i=0;i<4;i++){
        int row = wr + i*16 + lr;
        af[i] = *(const v4i*)(As + row*128 + (((kk*4+lg) ^ (row&7))*16));
      }
#pragma unroll
      for (int j=0;j<4;j++){
        int row = wc + j*16 + lr;
        bf[j] = *(const v4i*)(Bs + row*128 + (((kk*4+lg) ^ (row&7))*16));
      }
#pragma unroll
      for (int i=0;i<4;i++)
#pragma unroll
        for (int j=0;j<4;j++)
          acc[i][j] = __builtin_amdgcn_mfma_i32_16x16x64_i8(af[i], bf[j], acc[i][j], 0, 0, 0);
    }
    __syncthreads();
  }
#pragma unroll
  for (int i=0;i<4;i++){
#pragma unroll
    for (int r=0;r<4;r++){
      int lrow = wr + i*16 + lg*4 + r;
      float f = inv_sx[bm0 + lrow] * inv_sw;
      size_t o = (size_t)(bm0 + lrow) * N + bn0;
#pragma unroll
      for (int j=0;j<4;j++)
        out[o + wc + j*16 + lr] = (float)acc[i][j][r] * f;
    }
  }
}

// ---------------- launch ----------------
extern "C" void kernel_launch(void* const* d_in, const int* in_sizes, int n_in,
                              void* d_out, int out_size, void* d_ws, size_t ws_size,
                              hipStream_t stream) {
  const float* x      = (const float*)d_in[0];   // [4,4096,2048]
  const float* w_gate = (const float*)d_in[1];   // [11264,2048]
  const float* g_gate = (const float*)d_in[2];   // [2048]
  const float* w_down = (const float*)d_in[3];   // [2048,5632]
  const float* g_down = (const float*)d_in[4];   // [5632]
  float* out = (float*)d_out;                    // [4,4096,2048]

  char* p = (char*)d_ws;
  float* hdr      = (float*)p;          // [0]=sc_wg [1]=1/sc_wg [2]=sc_wd [3]=1/sc_wd
  float* partials = (float*)(p + 64);   // 2048 floats
  size_t off = 8448;
  signed char* wqg = (signed char*)(p + off); off += 23068672;   // [11264][2048]
  signed char* wqd = (signed char*)(p + off); off += 11534336;   // [2048][5632]
  signed char* xq1 = (signed char*)(p + off); off += 33554432;   // [16384][2048]
  signed char* xq2 = (signed char*)(p + off); off += 92274688;   // [16384][5632]
  float* isx1 = (float*)(p + off); off += 65536;
  float* isx2 = (float*)(p + off); off += 65536;
  __hip_bfloat16* sg = (__hip_bfloat16*)(p + off); off += 184549376; // [16384][5632]

  reduce_abs_kernel<<<1024,256,0,stream>>>(w_gate, 23068672/4, partials);
  reduce_abs_kernel<<<1024,256,0,stream>>>(w_down, 11534336/4, partials+1024);
  finalize_scales_kernel<<<1,256,0,stream>>>(partials, hdr);
  quant_w_kernel<<<2048,256,0,stream>>>(w_gate, wqg, 23068672/4, hdr, 0);
  quant_w_kernel<<<1024,256,0,stream>>>(w_down, wqd, 11534336/4, hdr, 2);
  rms_quant_x_kernel<<<16384,256,0,stream>>>(x, g_gate, xq1, isx1);
  gemm1_swiglu_kernel<<<dim3(44,128),512,0,stream>>>(xq1, wqg, isx1, hdr, sg);
  rms_quant_sg_kernel<<<16384,256,0,stream>>>(sg, g_down, xq2, isx2);
  gemm2_kernel<<<dim3(16,128),256,0,stream>>>(xq2, wqd, isx2, hdr, out);
}

// Round 3
// 882.587 us; speedup vs baseline: 2.6272x; 1.1871x over previous
//
#include <hip/hip_runtime.h>
#include <hip/hip_bf16.h>

typedef int v4i __attribute__((ext_vector_type(4)));

#define DEV __device__ __forceinline__

DEV void gload16(const void* g, void* l){
  __builtin_amdgcn_global_load_lds((const __attribute__((address_space(1))) unsigned int*)g,
                                   (__attribute__((address_space(3))) unsigned int*)l, 16, 0, 0);
}

// ---------------- block reductions (blockDim == 256) ----------------
DEV float block_sum256(float v, float* red){
#pragma unroll
  for (int o=32;o>0;o>>=1) v += __shfl_down(v,o);
  int w = threadIdx.x>>6;
  if ((threadIdx.x&63)==0) red[w]=v;
  __syncthreads();
  v = red[0]+red[1]+red[2]+red[3];
  __syncthreads();
  return v;
}
DEV float block_max256(float v, float* red){
#pragma unroll
  for (int o=32;o>0;o>>=1) v = fmaxf(v,__shfl_down(v,o));
  int w = threadIdx.x>>6;
  if ((threadIdx.x&63)==0) red[w]=v;
  __syncthreads();
  v = fmaxf(fmaxf(red[0],red[1]),fmaxf(red[2],red[3]));
  __syncthreads();
  return v;
}

// ---------------- weight scale reduction ----------------
__global__ __launch_bounds__(256) void reduce_abs_kernel(const float* __restrict__ w, long n4,
                                                         float* __restrict__ partials){
  __shared__ float red[4];
  const float4* w4 = (const float4*)w;
  float s = 0.f;
  for (long i = (long)blockIdx.x*256 + threadIdx.x; i < n4; i += (long)gridDim.x*256){
    float4 v = w4[i];
    s += fabsf(v.x)+fabsf(v.y)+fabsf(v.z)+fabsf(v.w);
  }
  s = block_sum256(s, red);
  if (threadIdx.x==0) partials[blockIdx.x]=s;
}

__global__ __launch_bounds__(256) void finalize_scales_kernel(const float* __restrict__ partials,
                                                              float* __restrict__ hdr){
  __shared__ float red[4];
  float s1=0.f, s2=0.f;
  for (int i=threadIdx.x;i<1024;i+=256){ s1+=partials[i]; s2+=partials[i+1024]; }
  s1 = block_sum256(s1, red);
  s2 = block_sum256(s2, red);
  if (threadIdx.x==0){
    float m1 = s1 / 23068672.0f;            // mean |w_gate|
    float sc1 = 1.0f / fmaxf(m1, 1e-5f);
    hdr[0]=sc1; hdr[1]=1.0f/sc1;
    float m2 = s2 / 11534336.0f;            // mean |w_down|
    float sc2 = 1.0f / fmaxf(m2, 1e-5f);
    hdr[2]=sc2; hdr[3]=1.0f/sc2;
  }
}

// ---------------- ternary weight quant ----------------
__global__ __launch_bounds__(256) void quant_w_kernel(const float* __restrict__ w,
                                                      signed char* __restrict__ wq, long n4,
                                                      const float* __restrict__ hdr, int hi){
  float scale = hdr[hi];
  const float4* w4 = (const float4*)w;
  unsigned* o4 = (unsigned*)wq;
  for (long i = (long)blockIdx.x*256 + threadIdx.x; i < n4; i += (long)gridDim.x*256){
    float4 v = w4[i];
    int q0 = (int)fminf(fmaxf(rintf(v.x*scale),-1.f),1.f);
    int q1 = (int)fminf(fmaxf(rintf(v.y*scale),-1.f),1.f);
    int q2 = (int)fminf(fmaxf(rintf(v.z*scale),-1.f),1.f);
    int q3 = (int)fminf(fmaxf(rintf(v.w*scale),-1.f),1.f);
    unsigned pk = (q0&0xff) | ((q1&0xff)<<8) | ((q2&0xff)<<16) | ((q3&0xff)<<24);
    o4[i] = pk;
  }
}

// ---------------- RMSNorm + act quant (fp32 input, D=2048) ----------------
__global__ __launch_bounds__(256) void rms_quant_x_kernel(const float* __restrict__ x,
                                                          const float* __restrict__ g,
                                                          signed char* __restrict__ xq,
                                                          float* __restrict__ isx){
  __shared__ float red[4];
  const int row = blockIdx.x, t = threadIdx.x;
  const float* xr = x + (size_t)row*2048 + t*8;
  float4 a = *(const float4*)xr;
  float4 b = *(const float4*)(xr+4);
  float xv[8] = {a.x,a.y,a.z,a.w,b.x,b.y,b.z,b.w};
  float ss = 0.f;
#pragma unroll
  for (int i=0;i<8;i++) ss += xv[i]*xv[i];
  ss = block_sum256(ss, red);
  float rs = rsqrtf(ss*(1.0f/2048.0f) + 1e-6f);
  const float* gr = g + t*8;
  float4 ga = *(const float4*)gr;
  float4 gb = *(const float4*)(gr+4);
  float gv[8] = {ga.x,ga.y,ga.z,ga.w,gb.x,gb.y,gb.z,gb.w};
  float xn[8]; float m = 0.f;
#pragma unroll
  for (int i=0;i<8;i++){ xn[i] = xv[i]*rs*gv[i]; m = fmaxf(m, fabsf(xn[i])); }
  m = block_max256(m, red);
  float scale = 127.0f / fmaxf(m, 1e-5f);
  unsigned long long pk = 0;
#pragma unroll
  for (int i=0;i<8;i++){
    int q = (int)fminf(fmaxf(rintf(xn[i]*scale), -128.0f), 127.0f);
    pk |= (unsigned long long)(unsigned char)(signed char)q << (8*i);
  }
  *(unsigned long long*)(xq + (size_t)row*2048 + t*8) = pk;
  if (t==0) isx[row] = 1.0f/scale;
}

// ---------------- RMSNorm + act quant (bf16 swiglu input, I=5632) ----------------
__global__ __launch_bounds__(256) void rms_quant_sg_kernel(const __hip_bfloat16* __restrict__ sg,
                                                           const float* __restrict__ g,
                                                           signed char* __restrict__ xq,
                                                           float* __restrict__ isx){
  __shared__ float red[4];
  const int row = blockIdx.x, t = threadIdx.x;
  const unsigned* sr = (const unsigned*)(sg + (size_t)row*5632);
  float s[22];
  float ss = 0.f;
#pragma unroll
  for (int i=0;i<11;i++){
    unsigned u = sr[t + i*256];
    float f0 = __uint_as_float(u<<16);
    float f1 = __uint_as_float(u & 0xffff0000u);
    s[2*i]=f0; s[2*i+1]=f1;
    ss += f0*f0 + f1*f1;
  }
  ss = block_sum256(ss, red);
  float rs = rsqrtf(ss*(1.0f/5632.0f) + 1e-6f);
  const float2* g2 = (const float2*)g;
  float xn[22]; float m = 0.f;
#pragma unroll
  for (int i=0;i<11;i++){
    float2 gv = g2[t + i*256];
    xn[2*i]   = s[2*i]  *rs*gv.x;
    xn[2*i+1] = s[2*i+1]*rs*gv.y;
    m = fmaxf(m, fmaxf(fabsf(xn[2*i]), fabsf(xn[2*i+1])));
  }
  m = block_max256(m, red);
  float scale = 127.0f / fmaxf(m, 1e-5f);
  short* o2 = (short*)(xq + (size_t)row*5632);
#pragma unroll
  for (int i=0;i<11;i++){
    int q0 = (int)fminf(fmaxf(rintf(xn[2*i]  *scale), -128.0f), 127.0f);
    int q1 = (int)fminf(fmaxf(rintf(xn[2*i+1]*scale), -128.0f), 127.0f);
    o2[t + i*256] = (short)((q0 & 0xff) | ((q1 & 0xff) << 8));
  }
  if (t==0) isx[row] = 1.0f/scale;
}

// ---------------- GEMM1: int8 MFMA, double-buffered counted-vmcnt pipeline ----------------
// A: xq1 [16384][2048], B: wq_gate [11264][2048]
// waves 0-3 compute gate cols [bc0,bc0+128), waves 4-7 v cols [5632+bc0,...)
// LDS: 2 x 48KB buffers (As 16KB + Bs 32KB), XOR-swizzled via global source.
__global__ __launch_bounds__(512) void gemm1_swiglu_kernel(const signed char* __restrict__ A,
                                                           const signed char* __restrict__ B,
                                                           const float* __restrict__ inv_sx,
                                                           const float* __restrict__ hdr,
                                                           __hip_bfloat16* __restrict__ out){
  constexpr int K = 2048;
  constexpr int NI = 5632;
  constexpr int NT = 16;            // K/128
  __shared__ __align__(16) unsigned char smem[98304];   // 2 x 49152

  const int t = threadIdx.x;
  const int lid = blockIdx.x + blockIdx.y * gridDim.x;  // 0..5631
  const int nid = (lid & 7) * 704 + (lid >> 3);         // bijective XCD swizzle
  const int bm0 = (nid / 44) * 128;
  const int bc0 = (nid % 44) * 128;
  const int w = t >> 6, l = t & 63;
  const int ts = w >> 2;          // 0 = gate waves, 1 = v waves
  const int wv = w & 3;
  const int wr = (wv >> 1) * 64, wc = (wv & 1) * 64;
  const int lr = l & 15, lg = l >> 4;

  const float inv_sw = hdr[1];

  const signed char* aSrc[2]; int aOff[2];
#pragma unroll
  for (int i=0;i<2;i++){
    int c = t + i*512; int r = c>>3, k = c&7;
    aSrc[i] = A + (size_t)(bm0 + r)*K + (k ^ (r&7))*16;
    aOff[i] = c*16;
  }
  const signed char* bSrc[4]; int bOff[4];
#pragma unroll
  for (int i=0;i<4;i++){
    int c = t + i*512; int tile = c>>10, r = (c>>3)&127, k = c&7;
    int grow = (tile ? NI : 0) + bc0 + r;
    bSrc[i] = B + (size_t)grow*K + (k ^ (r&7))*16;
    bOff[i] = 16384 + c*16;
  }

  v4i acc[4][4] = {};

#define STAGE1(BUF, KT) do{ unsigned char* _bb = smem + (BUF)*49152;              \
  _Pragma("unroll") for (int _i=0;_i<2;_i++) gload16(aSrc[_i] + (KT)*128, _bb + aOff[_i]); \
  _Pragma("unroll") for (int _i=0;_i<4;_i++) gload16(bSrc[_i] + (KT)*128, _bb + bOff[_i]); }while(0)

#define COMP1(BUF) do{                                                            \
  const signed char* _As = (const signed char*)smem + (BUF)*49152;                \
  const signed char* _Bs = _As + 16384;                                           \
  _Pragma("unroll") for (int kk=0;kk<2;++kk){                                     \
    v4i af[4], bf[4];                                                             \
    _Pragma("unroll") for (int i=0;i<4;i++){                                      \
      int row = wr + i*16 + lr;                                                   \
      af[i] = *(const v4i*)(_As + row*128 + (((kk*4+lg) ^ (row&7))*16));          \
    }                                                                             \
    _Pragma("unroll") for (int j=0;j<4;j++){                                      \
      int row = wc + j*16 + lr;                                                   \
      bf[j] = *(const v4i*)(_Bs + ts*16384 + row*128 + (((kk*4+lg) ^ (row&7))*16));\
    }                                                                             \
    _Pragma("unroll") for (int i=0;i<4;i++)                                       \
      _Pragma("unroll") for (int j=0;j<4;j++)                                     \
        acc[i][j] = __builtin_amdgcn_mfma_i32_16x16x64_i8(af[i], bf[j], acc[i][j], 0, 0, 0); \
  } }while(0)

  STAGE1(0, 0);
  STAGE1(1, 1);
  for (int kt = 0; kt < NT-2; kt += 2){
    asm volatile("s_waitcnt vmcnt(6)" ::: "memory");
    __builtin_amdgcn_s_barrier();
    __builtin_amdgcn_sched_barrier(0);
    COMP1(0);
    __builtin_amdgcn_sched_barrier(0);
    __builtin_amdgcn_s_barrier();
    STAGE1(0, kt+2);
    asm volatile("s_waitcnt vmcnt(6)" ::: "memory");
    __builtin_amdgcn_s_barrier();
    __builtin_amdgcn_sched_barrier(0);
    COMP1(1);
    __builtin_amdgcn_sched_barrier(0);
    __builtin_amdgcn_s_barrier();
    STAGE1(1, kt+3);
  }
  asm volatile("s_waitcnt vmcnt(6)" ::: "memory");
  __builtin_amdgcn_s_barrier();
  __builtin_amdgcn_sched_barrier(0);
  COMP1(0);
  __builtin_amdgcn_sched_barrier(0);
  __builtin_amdgcn_s_barrier();
  asm volatile("s_waitcnt vmcnt(0)" ::: "memory");
  __builtin_amdgcn_s_barrier();
  __builtin_amdgcn_sched_barrier(0);
  COMP1(1);
  __builtin_amdgcn_sched_barrier(0);

  // --- epilogue: v exchange (f32) -> swish -> bf16 tile -> coalesced store ---
  float* vex = (float*)smem;                      // [128][128] f32 (64KB of 96KB)
  __syncthreads();
  if (ts == 1){
#pragma unroll
    for (int i=0;i<4;i++){
#pragma unroll
      for (int r=0;r<4;r++){
        int lrow = wr + i*16 + lg*4 + r;
        float f = inv_sx[bm0 + lrow] * inv_sw;
#pragma unroll
        for (int j=0;j<4;j++)
          vex[lrow*128 + wc + j*16 + lr] = (float)acc[i][j][r] * f;
      }
    }
  }
  __syncthreads();
  if (ts == 0){             // compute swiglu into acc (reuse regs as f32 bits)
#pragma unroll
    for (int i=0;i<4;i++){
#pragma unroll
      for (int r=0;r<4;r++){
        int lrow = wr + i*16 + lg*4 + r;
        float f = inv_sx[bm0 + lrow] * inv_sw;
#pragma unroll
        for (int j=0;j<4;j++){
          float gv = (float)acc[i][j][r] * f;
          float vv = vex[lrow*128 + wc + j*16 + lr];
          float sw = gv / (1.0f + expf(-gv)) * vv;
          acc[i][j][r] = __float_as_int(sw);
        }
      }
    }
  }
  __syncthreads();          // all vex reads done; smem reusable as bf16 tile
  __hip_bfloat16* obuf = (__hip_bfloat16*)smem;   // [128][128] bf16, 32KB
  if (ts == 0){
#pragma unroll
    for (int i=0;i<4;i++){
#pragma unroll
      for (int r=0;r<4;r++){
        int lrow = wr + i*16 + lg*4 + r;
#pragma unroll
        for (int j=0;j<4;j++)
          obuf[lrow*128 + wc + j*16 + lr] = __float2bfloat16(__int_as_float(acc[i][j][r]));
      }
    }
  }
  __syncthreads();
  // coalesced store: 16B/lane, 256B per row segment
#pragma unroll
  for (int it=0; it<4; ++it){
    int idx = t + it*512;
    int row = idx >> 4, c16 = idx & 15;
    *(int4*)((char*)(out + (size_t)(bm0+row)*NI + bc0) + c16*16) =
        *(const int4*)((const char*)obuf + row*256 + c16*16);
  }
#undef STAGE1
#undef COMP1
}

// ---------------- GEMM2: int8 MFMA, double-buffered counted-vmcnt pipeline ----------------
// A: xq2 [16384][5632], B: wq_down [2048][5632], out fp32 [16384][2048]
__global__ __launch_bounds__(256) void gemm2_kernel(const signed char* __restrict__ A,
                                                    const signed char* __restrict__ B,
                                                    const float* __restrict__ inv_sx,
                                                    const float* __restrict__ hdr,
                                                    float* __restrict__ out){
  constexpr int K = 5632;
  constexpr int N = 2048;
  constexpr int NT = 44;            // K/128
  __shared__ __align__(16) unsigned char smem[65536];   // 2 x 32768

  const int t = threadIdx.x;
  const int lid = blockIdx.x + blockIdx.y * gridDim.x;  // 0..2047
  const int nid = (lid & 7) * 256 + (lid >> 3);         // bijective XCD swizzle
  const int bm0 = (nid >> 4) * 128;
  const int bn0 = (nid & 15) * 128;
  const int w = t >> 6, l = t & 63;
  const int wr = (w >> 1) * 64, wc = (w & 1) * 64;
  const int lr = l & 15, lg = l >> 4;

  const float inv_sw = hdr[3];

  const signed char *aSrc[4], *bSrc[4]; int aOff[4], bOff[4];
#pragma unroll
  for (int i=0;i<4;i++){
    int c = t + i*256; int r = c>>3, k = c&7;
    aSrc[i] = A + (size_t)(bm0 + r)*K + (k ^ (r&7))*16;
    bSrc[i] = B + (size_t)(bn0 + r)*K + (k ^ (r&7))*16;
    aOff[i] = c*16;
    bOff[i] = 16384 + c*16;
  }

  v4i acc[4][4] = {};

#define STAGE2(BUF, KT) do{ unsigned char* _bb = smem + (BUF)*32768;              \
  _Pragma("unroll") for (int _i=0;_i<4;_i++){                                     \
    gload16(aSrc[_i] + (KT)*128, _bb + aOff[_i]);                                 \
    gload16(bSrc[_i] + (KT)*128, _bb + bOff[_i]); } }while(0)

#define COMP2(BUF) do{                                                            \
  const signed char* _As = (const signed char*)smem + (BUF)*32768;                \
  const signed char* _Bs = _As + 16384;                                           \
  _Pragma("unroll") for (int kk=0;kk<2;++kk){                                     \
    v4i af[4], bf[4];                                                             \
    _Pragma("unroll") for (int i=0;i<4;i++){                                      \
      int row = wr + i*16 + lr;                                                   \
      af[i] = *(const v4i*)(_As + row*128 + (((kk*4+lg) ^ (row&7))*16));          \
    }                                                                             \
    _Pragma("unroll") for (int j=0;j<4;j++){                                      \
      int row = wc + j*16 + lr;                                                   \
      bf[j] = *(const v4i*)(_Bs + row*128 + (((kk*4+lg) ^ (row&7))*16));          \
    }                                                                             \
    _Pragma("unroll") for (int i=0;i<4;i++)                                       \
      _Pragma("unroll") for (int j=0;j<4;j++)                                     \
        acc[i][j] = __builtin_amdgcn_mfma_i32_16x16x64_i8(af[i], bf[j], acc[i][j], 0, 0, 0); \
  } }while(0)

  STAGE2(0, 0);
  STAGE2(1, 1);
  for (int kt = 0; kt < NT-2; kt += 2){
    asm volatile("s_waitcnt vmcnt(8)" ::: "memory");
    __builtin_amdgcn_s_barrier();
    __builtin_amdgcn_sched_barrier(0);
    COMP2(0);
    __builtin_amdgcn_sched_barrier(0);
    __builtin_amdgcn_s_barrier();
    STAGE2(0, kt+2);
    asm volatile("s_waitcnt vmcnt(8)" ::: "memory");
    __builtin_amdgcn_s_barrier();
    __builtin_amdgcn_sched_barrier(0);
    COMP2(1);
    __builtin_amdgcn_sched_barrier(0);
    __builtin_amdgcn_s_barrier();
    STAGE2(1, kt+3);
  }
  asm volatile("s_waitcnt vmcnt(8)" ::: "memory");
  __builtin_amdgcn_s_barrier();
  __builtin_amdgcn_sched_barrier(0);
  COMP2(0);
  __builtin_amdgcn_sched_barrier(0);
  __builtin_amdgcn_s_barrier();
  asm volatile("s_waitcnt vmcnt(0)" ::: "memory");
  __builtin_amdgcn_s_barrier();
  __builtin_amdgcn_sched_barrier(0);
  COMP2(1);
  __builtin_amdgcn_sched_barrier(0);

#pragma unroll
  for (int i=0;i<4;i++){
#pragma unroll
    for (int r=0;r<4;r++){
      int lrow = wr + i*16 + lg*4 + r;
      float f = inv_sx[bm0 + lrow] * inv_sw;
      size_t o = (size_t)(bm0 + lrow) * N + bn0;
#pragma unroll
      for (int j=0;j<4;j++)
        out[o + wc + j*16 + lr] = (float)acc[i][j][r] * f;
    }
  }
#undef STAGE2
#undef COMP2
}

// ---------------- launch ----------------
extern "C" void kernel_launch(void* const* d_in, const int* in_sizes, int n_in,
                              void* d_out, int out_size, void* d_ws, size_t ws_size,
                              hipStream_t stream) {
  const float* x      = (const float*)d_in[0];   // [4,4096,2048]
  const float* w_gate = (const float*)d_in[1];   // [11264,2048]
  const float* g_gate = (const float*)d_in[2];   // [2048]
  const float* w_down = (const float*)d_in[3];   // [2048,5632]
  const float* g_down = (const float*)d_in[4];   // [5632]
  float* out = (float*)d_out;                    // [4,4096,2048]

  char* p = (char*)d_ws;
  float* hdr      = (float*)p;          // [0]=sc_wg [1]=1/sc_wg [2]=sc_wd [3]=1/sc_wd
  float* partials = (float*)(p + 64);   // 2048 floats
  size_t off = 8448;
  signed char* wqg = (signed char*)(p + off); off += 23068672;   // [11264][2048]
  signed char* wqd = (signed char*)(p + off); off += 11534336;   // [2048][5632]
  signed char* xq1 = (signed char*)(p + off); off += 33554432;   // [16384][2048]
  signed char* xq2 = (signed char*)(p + off); off += 92274688;   // [16384][5632]
  float* isx1 = (float*)(p + off); off += 65536;
  float* isx2 = (float*)(p + off); off += 65536;
  __hip_bfloat16* sg = (__hip_bfloat16*)(p + off); off += 184549376; // [16384][5632]

  reduce_abs_kernel<<<1024,256,0,stream>>>(w_gate, 23068672/4, partials);
  reduce_abs_kernel<<<1024,256,0,stream>>>(w_down, 11534336/4, partials+1024);
  finalize_scales_kernel<<<1,256,0,stream>>>(partials, hdr);
  quant_w_kernel<<<2048,256,0,stream>>>(w_gate, wqg, 23068672/4, hdr, 0);
  quant_w_kernel<<<1024,256,0,stream>>>(w_down, wqd, 11534336/4, hdr, 2);
  rms_quant_x_kernel<<<16384,256,0,stream>>>(x, g_gate, xq1, isx1);
  gemm1_swiglu_kernel<<<dim3(44,128),512,0,stream>>>(xq1, wqg, isx1, hdr, sg);
  rms_quant_sg_kernel<<<16384,256,0,stream>>>(sg, g_down, xq2, isx2);
  gemm2_kernel<<<dim3(16,128),256,0,stream>>>(xq2, wqd, isx2, hdr, out);
}

// Round 4
// 829.069 us; speedup vs baseline: 2.7968x; 1.0646x over previous
//
#include <hip/hip_runtime.h>
#include <hip/hip_bf16.h>

typedef int v4i __attribute__((ext_vector_type(4)));

#define DEV __device__ __forceinline__

DEV void gload16(const void* g, void* l){
  __builtin_amdgcn_global_load_lds((const __attribute__((address_space(1))) unsigned int*)g,
                                   (__attribute__((address_space(3))) unsigned int*)l, 16, 0, 0);
}

// ---------------- block reductions (blockDim == 256) ----------------
DEV float block_sum256(float v, float* red){
#pragma unroll
  for (int o=32;o>0;o>>=1) v += __shfl_down(v,o);
  int w = threadIdx.x>>6;
  if ((threadIdx.x&63)==0) red[w]=v;
  __syncthreads();
  v = red[0]+red[1]+red[2]+red[3];
  __syncthreads();
  return v;
}
DEV float block_max256(float v, float* red){
#pragma unroll
  for (int o=32;o>0;o>>=1) v = fmaxf(v,__shfl_down(v,o));
  int w = threadIdx.x>>6;
  if ((threadIdx.x&63)==0) red[w]=v;
  __syncthreads();
  v = fmaxf(fmaxf(red[0],red[1]),fmaxf(red[2],red[3]));
  __syncthreads();
  return v;
}

// ---------------- weight scale reduction ----------------
__global__ __launch_bounds__(256) void reduce_abs_kernel(const float* __restrict__ w, long n4,
                                                         float* __restrict__ partials){
  __shared__ float red[4];
  const float4* w4 = (const float4*)w;
  float s = 0.f;
  for (long i = (long)blockIdx.x*256 + threadIdx.x; i < n4; i += (long)gridDim.x*256){
    float4 v = w4[i];
    s += fabsf(v.x)+fabsf(v.y)+fabsf(v.z)+fabsf(v.w);
  }
  s = block_sum256(s, red);
  if (threadIdx.x==0) partials[blockIdx.x]=s;
}

__global__ __launch_bounds__(256) void finalize_scales_kernel(const float* __restrict__ partials,
                                                              float* __restrict__ hdr){
  __shared__ float red[4];
  float s1=0.f, s2=0.f;
  for (int i=threadIdx.x;i<1024;i+=256){ s1+=partials[i]; s2+=partials[i+1024]; }
  s1 = block_sum256(s1, red);
  s2 = block_sum256(s2, red);
  if (threadIdx.x==0){
    float m1 = s1 / 23068672.0f;            // mean |w_gate|
    float sc1 = 1.0f / fmaxf(m1, 1e-5f);
    hdr[0]=sc1; hdr[1]=1.0f/sc1;
    float m2 = s2 / 11534336.0f;            // mean |w_down|
    float sc2 = 1.0f / fmaxf(m2, 1e-5f);
    hdr[2]=sc2; hdr[3]=1.0f/sc2;
  }
}

// ---------------- ternary weight quant ----------------
__global__ __launch_bounds__(256) void quant_w_kernel(const float* __restrict__ w,
                                                      signed char* __restrict__ wq, long n4,
                                                      const float* __restrict__ hdr, int hi){
  float scale = hdr[hi];
  const float4* w4 = (const float4*)w;
  unsigned* o4 = (unsigned*)wq;
  for (long i = (long)blockIdx.x*256 + threadIdx.x; i < n4; i += (long)gridDim.x*256){
    float4 v = w4[i];
    int q0 = (int)fminf(fmaxf(rintf(v.x*scale),-1.f),1.f);
    int q1 = (int)fminf(fmaxf(rintf(v.y*scale),-1.f),1.f);
    int q2 = (int)fminf(fmaxf(rintf(v.z*scale),-1.f),1.f);
    int q3 = (int)fminf(fmaxf(rintf(v.w*scale),-1.f),1.f);
    unsigned pk = (q0&0xff) | ((q1&0xff)<<8) | ((q2&0xff)<<16) | ((q3&0xff)<<24);
    o4[i] = pk;
  }
}

// ---------------- RMSNorm + act quant (fp32 input, D=2048) ----------------
__global__ __launch_bounds__(256) void rms_quant_x_kernel(const float* __restrict__ x,
                                                          const float* __restrict__ g,
                                                          signed char* __restrict__ xq,
                                                          float* __restrict__ isx){
  __shared__ float red[4];
  const int row = blockIdx.x, t = threadIdx.x;
  const float* xr = x + (size_t)row*2048 + t*8;
  float4 a = *(const float4*)xr;
  float4 b = *(const float4*)(xr+4);
  float xv[8] = {a.x,a.y,a.z,a.w,b.x,b.y,b.z,b.w};
  float ss = 0.f;
#pragma unroll
  for (int i=0;i<8;i++) ss += xv[i]*xv[i];
  ss = block_sum256(ss, red);
  float rs = rsqrtf(ss*(1.0f/2048.0f) + 1e-6f);
  const float* gr = g + t*8;
  float4 ga = *(const float4*)gr;
  float4 gb = *(const float4*)(gr+4);
  float gv[8] = {ga.x,ga.y,ga.z,ga.w,gb.x,gb.y,gb.z,gb.w};
  float xn[8]; float m = 0.f;
#pragma unroll
  for (int i=0;i<8;i++){ xn[i] = xv[i]*rs*gv[i]; m = fmaxf(m, fabsf(xn[i])); }
  m = block_max256(m, red);
  float scale = 127.0f / fmaxf(m, 1e-5f);
  unsigned long long pk = 0;
#pragma unroll
  for (int i=0;i<8;i++){
    int q = (int)fminf(fmaxf(rintf(xn[i]*scale), -128.0f), 127.0f);
    pk |= (unsigned long long)(unsigned char)(signed char)q << (8*i);
  }
  *(unsigned long long*)(xq + (size_t)row*2048 + t*8) = pk;
  if (t==0) isx[row] = 1.0f/scale;
}

// ---------------- RMSNorm + act quant (bf16 swiglu input, I=5632) ----------------
__global__ __launch_bounds__(256) void rms_quant_sg_kernel(const __hip_bfloat16* __restrict__ sg,
                                                           const float* __restrict__ g,
                                                           signed char* __restrict__ xq,
                                                           float* __restrict__ isx){
  __shared__ float red[4];
  const int row = blockIdx.x, t = threadIdx.x;
  const unsigned* sr = (const unsigned*)(sg + (size_t)row*5632);
  float s[22];
  float ss = 0.f;
#pragma unroll
  for (int i=0;i<11;i++){
    unsigned u = sr[t + i*256];
    float f0 = __uint_as_float(u<<16);
    float f1 = __uint_as_float(u & 0xffff0000u);
    s[2*i]=f0; s[2*i+1]=f1;
    ss += f0*f0 + f1*f1;
  }
  ss = block_sum256(ss, red);
  float rs = rsqrtf(ss*(1.0f/5632.0f) + 1e-6f);
  const float2* g2 = (const float2*)g;
  float xn[22]; float m = 0.f;
#pragma unroll
  for (int i=0;i<11;i++){
    float2 gv = g2[t + i*256];
    xn[2*i]   = s[2*i]  *rs*gv.x;
    xn[2*i+1] = s[2*i+1]*rs*gv.y;
    m = fmaxf(m, fmaxf(fabsf(xn[2*i]), fabsf(xn[2*i+1])));
  }
  m = block_max256(m, red);
  float scale = 127.0f / fmaxf(m, 1e-5f);
  short* o2 = (short*)(xq + (size_t)row*5632);
#pragma unroll
  for (int i=0;i<11;i++){
    int q0 = (int)fminf(fmaxf(rintf(xn[2*i]  *scale), -128.0f), 127.0f);
    int q1 = (int)fminf(fmaxf(rintf(xn[2*i+1]*scale), -128.0f), 127.0f);
    o2[t + i*256] = (short)((q0 & 0xff) | ((q1 & 0xff) << 8));
  }
  if (t==0) isx[row] = 1.0f/scale;
}

// ---------------- GEMM1: 256-row tile, int8 MFMA, dbuf counted-vmcnt ----------------
// A: xq1 [16384][2048], B: wq_gate [11264][2048]
// Block tile: rows [bm0,bm0+256), gate cols [bc0,bc0+128) (waves 0-3),
// v cols [5632+bc0,...) (waves 4-7). Wave w owns 64 rows x 128 cols.
// LDS: 2 x 64KB buffers (As 256x128 = 32KB + Bs 2x128x128 = 32KB).
__global__ __launch_bounds__(512) void gemm1_swiglu_kernel(const signed char* __restrict__ A,
                                                           const signed char* __restrict__ B,
                                                           const float* __restrict__ inv_sx,
                                                           const float* __restrict__ hdr,
                                                           __hip_bfloat16* __restrict__ out){
  constexpr int K = 2048;
  constexpr int NI = 5632;
  constexpr int NT = 16;            // K/128
  __shared__ __align__(16) unsigned char smem[131072];   // 2 x 65536

  const int t = threadIdx.x;
  const int lid = blockIdx.x + blockIdx.y * gridDim.x;  // 0..2815
  const int nid = (lid & 7) * 352 + (lid >> 3);         // bijective XCD swizzle (2816%8==0)
  const int bm0 = (nid / 44) * 256;
  const int bc0 = (nid % 44) * 128;
  const int w = t >> 6, l = t & 63;
  const int ts = w >> 2;          // 0 = gate waves, 1 = v waves
  const int wv = w & 3;
  const int wr = wv * 64;         // wave's 64-row band
  const int lr = l & 15, lg = l >> 4;

  const float inv_sw = hdr[1];

  const signed char* aSrc[4]; int aOff[4];
#pragma unroll
  for (int i=0;i<4;i++){
    int c = t + i*512; int r = c>>3, k = c&7;      // r in [0,256)
    aSrc[i] = A + (size_t)(bm0 + r)*K + (k ^ (r&7))*16;
    aOff[i] = c*16;
  }
  const signed char* bSrc[4]; int bOff[4];
#pragma unroll
  for (int i=0;i<4;i++){
    int c = t + i*512; int tile = c>>10, r = (c>>3)&127, k = c&7;
    int grow = (tile ? NI : 0) + bc0 + r;
    bSrc[i] = B + (size_t)grow*K + (k ^ (r&7))*16;
    bOff[i] = 32768 + c*16;
  }

  v4i acc[4][8] = {};

#define STAGE1(BUF, KT) do{ unsigned char* _bb = smem + (BUF)*65536;              \
  _Pragma("unroll") for (int _i=0;_i<4;_i++) gload16(aSrc[_i] + (KT)*128, _bb + aOff[_i]); \
  _Pragma("unroll") for (int _i=0;_i<4;_i++) gload16(bSrc[_i] + (KT)*128, _bb + bOff[_i]); }while(0)

#define COMP1(BUF) do{                                                            \
  const signed char* _As = (const signed char*)smem + (BUF)*65536;                \
  const signed char* _Bs = _As + 32768;                                           \
  _Pragma("unroll") for (int kk=0;kk<2;++kk){                                     \
    v4i af[4], bf[8];                                                             \
    _Pragma("unroll") for (int i=0;i<4;i++){                                      \
      int row = wr + i*16 + lr;                                                   \
      af[i] = *(const v4i*)(_As + row*128 + (((kk*4+lg) ^ (row&7))*16));          \
    }                                                                             \
    _Pragma("unroll") for (int j=0;j<8;j++){                                      \
      int row = j*16 + lr;                                                        \
      bf[j] = *(const v4i*)(_Bs + ts*16384 + row*128 + (((kk*4+lg) ^ (row&7))*16));\
    }                                                                             \
    __builtin_amdgcn_s_setprio(1);                                                \
    _Pragma("unroll") for (int j=0;j<8;j++)                                       \
      _Pragma("unroll") for (int i=0;i<4;i++)                                     \
        acc[i][j] = __builtin_amdgcn_mfma_i32_16x16x64_i8(af[i], bf[j], acc[i][j], 0, 0, 0); \
    __builtin_amdgcn_s_setprio(0);                                                \
  } }while(0)

  STAGE1(0, 0);
  STAGE1(1, 1);
  for (int kt = 0; kt < NT-2; kt += 2){
    asm volatile("s_waitcnt vmcnt(8)" ::: "memory");
    __builtin_amdgcn_s_barrier();
    __builtin_amdgcn_sched_barrier(0);
    COMP1(0);
    __builtin_amdgcn_sched_barrier(0);
    __builtin_amdgcn_s_barrier();
    STAGE1(0, kt+2);
    asm volatile("s_waitcnt vmcnt(8)" ::: "memory");
    __builtin_amdgcn_s_barrier();
    __builtin_amdgcn_sched_barrier(0);
    COMP1(1);
    __builtin_amdgcn_sched_barrier(0);
    __builtin_amdgcn_s_barrier();
    STAGE1(1, kt+3);
  }
  asm volatile("s_waitcnt vmcnt(8)" ::: "memory");
  __builtin_amdgcn_s_barrier();
  __builtin_amdgcn_sched_barrier(0);
  COMP1(0);
  __builtin_amdgcn_sched_barrier(0);
  __builtin_amdgcn_s_barrier();
  asm volatile("s_waitcnt vmcnt(0)" ::: "memory");
  __builtin_amdgcn_s_barrier();
  __builtin_amdgcn_sched_barrier(0);
  COMP1(1);
  __builtin_amdgcn_sched_barrier(0);

  // --- epilogue: v exchange (f32, 256x128 = 128KB) -> swish -> bf16 -> store ---
  float* vex = (float*)smem;
  __syncthreads();
  if (ts == 1){
#pragma unroll
    for (int i=0;i<4;i++){
#pragma unroll
      for (int r=0;r<4;r++){
        int lrow = wr + i*16 + lg*4 + r;
        float f = inv_sx[bm0 + lrow] * inv_sw;
#pragma unroll
        for (int j=0;j<8;j++)
          vex[lrow*128 + j*16 + lr] = (float)acc[i][j][r] * f;
      }
    }
  }
  __syncthreads();
  if (ts == 0){             // compute swiglu into acc (reuse regs as f32 bits)
#pragma unroll
    for (int i=0;i<4;i++){
#pragma unroll
      for (int r=0;r<4;r++){
        int lrow = wr + i*16 + lg*4 + r;
        float f = inv_sx[bm0 + lrow] * inv_sw;
#pragma unroll
        for (int j=0;j<8;j++){
          float gv = (float)acc[i][j][r] * f;
          float vv = vex[lrow*128 + j*16 + lr];
          float sw = gv / (1.0f + expf(-gv)) * vv;
          acc[i][j][r] = __float_as_int(sw);
        }
      }
    }
  }
  __syncthreads();          // all vex reads done; smem reusable as bf16 tile
  __hip_bfloat16* obuf = (__hip_bfloat16*)smem;   // [256][128] bf16, 64KB
  if (ts == 0){
#pragma unroll
    for (int i=0;i<4;i++){
#pragma unroll
      for (int r=0;r<4;r++){
        int lrow = wr + i*16 + lg*4 + r;
#pragma unroll
        for (int j=0;j<8;j++)
          obuf[lrow*128 + j*16 + lr] = __float2bfloat16(__int_as_float(acc[i][j][r]));
      }
    }
  }
  __syncthreads();
  // coalesced store: 16B/lane, 256B per row segment, 256 rows
#pragma unroll
  for (int it=0; it<8; ++it){
    int idx = t + it*512;
    int row = idx >> 4, c16 = idx & 15;
    *(int4*)((char*)(out + (size_t)(bm0+row)*NI + bc0) + c16*16) =
        *(const int4*)((const char*)obuf + row*256 + c16*16);
  }
#undef STAGE1
#undef COMP1
}

// ---------------- GEMM2: int8 MFMA, double-buffered counted-vmcnt pipeline ----------------
// A: xq2 [16384][5632], B: wq_down [2048][5632], out fp32 [16384][2048]
__global__ __launch_bounds__(256) void gemm2_kernel(const signed char* __restrict__ A,
                                                    const signed char* __restrict__ B,
                                                    const float* __restrict__ inv_sx,
                                                    const float* __restrict__ hdr,
                                                    float* __restrict__ out){
  constexpr int K = 5632;
  constexpr int N = 2048;
  constexpr int NT = 44;            // K/128
  __shared__ __align__(16) unsigned char smem[65536];   // 2 x 32768

  const int t = threadIdx.x;
  const int lid = blockIdx.x + blockIdx.y * gridDim.x;  // 0..2047
  const int nid = (lid & 7) * 256 + (lid >> 3);         // bijective XCD swizzle
  const int bm0 = (nid >> 4) * 128;
  const int bn0 = (nid & 15) * 128;
  const int w = t >> 6, l = t & 63;
  const int wr = (w >> 1) * 64, wc = (w & 1) * 64;
  const int lr = l & 15, lg = l >> 4;

  const float inv_sw = hdr[3];

  const signed char *aSrc[4], *bSrc[4]; int aOff[4], bOff[4];
#pragma unroll
  for (int i=0;i<4;i++){
    int c = t + i*256; int r = c>>3, k = c&7;
    aSrc[i] = A + (size_t)(bm0 + r)*K + (k ^ (r&7))*16;
    bSrc[i] = B + (size_t)(bn0 + r)*K + (k ^ (r&7))*16;
    aOff[i] = c*16;
    bOff[i] = 16384 + c*16;
  }

  v4i acc[4][4] = {};

#define STAGE2(BUF, KT) do{ unsigned char* _bb = smem + (BUF)*32768;              \
  _Pragma("unroll") for (int _i=0;_i<4;_i++){                                     \
    gload16(aSrc[_i] + (KT)*128, _bb + aOff[_i]);                                 \
    gload16(bSrc[_i] + (KT)*128, _bb + bOff[_i]); } }while(0)

#define COMP2(BUF) do{                                                            \
  const signed char* _As = (const signed char*)smem + (BUF)*32768;                \
  const signed char* _Bs = _As + 16384;                                           \
  _Pragma("unroll") for (int kk=0;kk<2;++kk){                                     \
    v4i af[4], bf[4];                                                             \
    _Pragma("unroll") for (int i=0;i<4;i++){                                      \
      int row = wr + i*16 + lr;                                                   \
      af[i] = *(const v4i*)(_As + row*128 + (((kk*4+lg) ^ (row&7))*16));          \
    }                                                                             \
    _Pragma("unroll") for (int j=0;j<4;j++){                                      \
      int row = wc + j*16 + lr;                                                   \
      bf[j] = *(const v4i*)(_Bs + row*128 + (((kk*4+lg) ^ (row&7))*16));          \
    }                                                                             \
    __builtin_amdgcn_s_setprio(1);                                                \
    _Pragma("unroll") for (int i=0;i<4;i++)                                       \
      _Pragma("unroll") for (int j=0;j<4;j++)                                     \
        acc[i][j] = __builtin_amdgcn_mfma_i32_16x16x64_i8(af[i], bf[j], acc[i][j], 0, 0, 0); \
    __builtin_amdgcn_s_setprio(0);                                                \
  } }while(0)

  STAGE2(0, 0);
  STAGE2(1, 1);
  for (int kt = 0; kt < NT-2; kt += 2){
    asm volatile("s_waitcnt vmcnt(8)" ::: "memory");
    __builtin_amdgcn_s_barrier();
    __builtin_amdgcn_sched_barrier(0);
    COMP2(0);
    __builtin_amdgcn_sched_barrier(0);
    __builtin_amdgcn_s_barrier();
    STAGE2(0, kt+2);
    asm volatile("s_waitcnt vmcnt(8)" ::: "memory");
    __builtin_amdgcn_s_barrier();
    __builtin_amdgcn_sched_barrier(0);
    COMP2(1);
    __builtin_amdgcn_sched_barrier(0);
    __builtin_amdgcn_s_barrier();
    STAGE2(1, kt+3);
  }
  asm volatile("s_waitcnt vmcnt(8)" ::: "memory");
  __builtin_amdgcn_s_barrier();
  __builtin_amdgcn_sched_barrier(0);
  COMP2(0);
  __builtin_amdgcn_sched_barrier(0);
  __builtin_amdgcn_s_barrier();
  asm volatile("s_waitcnt vmcnt(0)" ::: "memory");
  __builtin_amdgcn_s_barrier();
  __builtin_amdgcn_sched_barrier(0);
  COMP2(1);
  __builtin_amdgcn_sched_barrier(0);

#pragma unroll
  for (int i=0;i<4;i++){
#pragma unroll
    for (int r=0;r<4;r++){
      int lrow = wr + i*16 + lg*4 + r;
      float f = inv_sx[bm0 + lrow] * inv_sw;
      size_t o = (size_t)(bm0 + lrow) * N + bn0;
#pragma unroll
      for (int j=0;j<4;j++)
        out[o + wc + j*16 + lr] = (float)acc[i][j][r] * f;
    }
  }
#undef STAGE2
#undef COMP2
}

// ---------------- launch ----------------
extern "C" void kernel_launch(void* const* d_in, const int* in_sizes, int n_in,
                              void* d_out, int out_size, void* d_ws, size_t ws_size,
                              hipStream_t stream) {
  const float* x      = (const float*)d_in[0];   // [4,4096,2048]
  const float* w_gate = (const float*)d_in[1];   // [11264,2048]
  const float* g_gate = (const float*)d_in[2];   // [2048]
  const float* w_down = (const float*)d_in[3];   // [2048,5632]
  const float* g_down = (const float*)d_in[4];   // [5632]
  float* out = (float*)d_out;                    // [4,4096,2048]

  char* p = (char*)d_ws;
  float* hdr      = (float*)p;          // [0]=sc_wg [1]=1/sc_wg [2]=sc_wd [3]=1/sc_wd
  float* partials = (float*)(p + 64);   // 2048 floats
  size_t off = 8448;
  signed char* wqg = (signed char*)(p + off); off += 23068672;   // [11264][2048]
  signed char* wqd = (signed char*)(p + off); off += 11534336;   // [2048][5632]
  signed char* xq1 = (signed char*)(p + off); off += 33554432;   // [16384][2048]
  signed char* xq2 = (signed char*)(p + off); off += 92274688;   // [16384][5632]
  float* isx1 = (float*)(p + off); off += 65536;
  float* isx2 = (float*)(p + off); off += 65536;
  __hip_bfloat16* sg = (__hip_bfloat16*)(p + off); off += 184549376; // [16384][5632]

  reduce_abs_kernel<<<1024,256,0,stream>>>(w_gate, 23068672/4, partials);
  reduce_abs_kernel<<<1024,256,0,stream>>>(w_down, 11534336/4, partials+1024);
  finalize_scales_kernel<<<1,256,0,stream>>>(partials, hdr);
  quant_w_kernel<<<2048,256,0,stream>>>(w_gate, wqg, 23068672/4, hdr, 0);
  quant_w_kernel<<<1024,256,0,stream>>>(w_down, wqd, 11534336/4, hdr, 2);
  rms_quant_x_kernel<<<16384,256,0,stream>>>(x, g_gate, xq1, isx1);
  gemm1_swiglu_kernel<<<dim3(44,64),512,0,stream>>>(xq1, wqg, isx1, hdr, sg);
  rms_quant_sg_kernel<<<16384,256,0,stream>>>(sg, g_down, xq2, isx2);
  gemm2_kernel<<<dim3(16,128),256,0,stream>>>(xq2, wqd, isx2, hdr, out);
}